// Round 1
// baseline (186.257 us; speedup 1.0000x reference)
//
#include <hip/hip_runtime.h>

// ---------------------------------------------------------------------------
// Sparse3DNA: x->QKV proj (bf16 MFMA GEMM), 3x3x3 causal window attention
// (+BOS), output proj. Shapes: b=2, T=4096 (4x32x32), DIM=512, 8 heads x 64.
// ---------------------------------------------------------------------------

#define T_TOK   4096
#define BATCH   2
#define MROWS   (BATCH * T_TOK)     // 8192
#define DIM     512
#define NQKV    1536

typedef unsigned short u16;
typedef unsigned int   u32;
typedef unsigned long long u64;
typedef __attribute__((ext_vector_type(8))) short short8;   // 8 bf16 (4 VGPR)
typedef __attribute__((ext_vector_type(4))) float f32x4;

__device__ __forceinline__ u16 f2bf(float f) {           // RNE float->bf16
    u32 u = __float_as_uint(f);
    return (u16)((u + 0x7fffu + ((u >> 16) & 1u)) >> 16);
}
__device__ __forceinline__ float b2f(u16 u) {
    return __uint_as_float(((u32)u) << 16);
}

__device__ __forceinline__ void gload_lds16(const void* g, void* l) {
    // async global->LDS, 16B/lane; LDS dest = wave-uniform base + lane*16
    __builtin_amdgcn_global_load_lds(
        (const __attribute__((address_space(1))) void*)g,
        (__attribute__((address_space(3))) void*)l, 16, 0, 0);
}

// ---------------------------------------------------------------------------
// cast kernels
// ---------------------------------------------------------------------------
__global__ void cast_x_kernel(const float4* __restrict__ x, u16* __restrict__ xb) {
    int i = blockIdx.x * 256 + threadIdx.x;      // 1,048,576 float4s
    float4 v = x[i];
    u64 pack = (u64)f2bf(v.x) | ((u64)f2bf(v.y) << 16) |
               ((u64)f2bf(v.z) << 32) | ((u64)f2bf(v.w) << 48);
    ((u64*)xb)[i] = pack;
}

// Wt[n][k] = [Wq | Wk | Wv](k, n)  (1536 x 512), Wot[n][k] = Wo[k][n]
__global__ void cast_w_kernel(const float* __restrict__ Wq, const float* __restrict__ Wkv,
                              const float* __restrict__ Wo,
                              u16* __restrict__ Wt, u16* __restrict__ Wot) {
    int idx = blockIdx.x * 256 + threadIdx.x;    // 1,048,576 total
    if (idx < 786432) {
        int k = idx / 1536, n = idx % 1536;      // coalesced reads
        float v = (n < 512) ? Wq[k * 512 + n] : Wkv[k * 1024 + (n - 512)];
        Wt[n * 512 + k] = f2bf(v);
    } else {
        int i2 = idx - 786432;
        int k = i2 >> 9, n = i2 & 511;
        Wot[n * 512 + k] = f2bf(Wo[k * 512 + n]);
    }
}

// ---------------------------------------------------------------------------
// NT GEMM: C(MxN) = A(MxK) * B(NxK)^T, K=512, bf16 in, fp32 acc.
// 128x128 tile / block, 4 waves (2x2), each wave 64x64 via 4x4 mfma 16x16x32.
// BK=32. LDS: A-tile 128x32 + B-tile 128x32 bf16, XOR-swizzled 16B chunks:
//   chunk(row r, kchunk c) -> slot r*4 + ((c + (r>>1)) & 3)
// so quad-structured ds_read_b128 lands 2-way on banks (free per m136).
// MODE 0: bf16 store. MODE 1: fp32 store + bias.
// ---------------------------------------------------------------------------
template <int MODE>
__global__ __launch_bounds__(256)
void gemm_nt(const u16* __restrict__ A, const u16* __restrict__ B,
             void* __restrict__ Cv, const float* __restrict__ bias,
             int lda, int ldb, int ldc) {
    constexpr int K = 512, BK = 32;
    __shared__ __align__(16) char lds[16384];    // 8KB A + 8KB B
    const int tid  = threadIdx.x;
    const int lane = tid & 63, wave = tid >> 6;
    const int quad = lane >> 4, mrow = lane & 15;
    const int wm = wave >> 1, wn = wave & 1;
    const int bm = blockIdx.y, bn = blockIdx.x;

    // --- staging address precompute (4 chunks of 16B per thread per K-step)
    const char* gptr[4];
    char*       lptr[4];
    #pragma unroll
    for (int it = 0; it < 4; ++it) {
        int c   = it * 256 + tid;               // chunk id, lane-consecutive
        int inB = (c >= 512);
        int a   = inB ? c - 512 : c;
        int r   = a >> 2;                        // tile row (0..127)
        int kc  = ((a & 3) - (r >> 1)) & 3;      // inverse swizzle
        int row = (inB ? bn : bm) * 128 + r;
        const u16* base = inB ? B : A;
        int ld = inB ? ldb : lda;
        gptr[it] = (const char*)(base + (size_t)row * ld + kc * 8);
        lptr[it] = (char*)lds + it * 4096 + wave * 1024;   // wave-uniform
    }
    // --- fragment LDS addresses (K-invariant)
    const short8* aLds[4];
    const short8* bLds[4];
    #pragma unroll
    for (int i = 0; i < 4; ++i) {
        int ra = wm * 64 + i * 16 + mrow;
        aLds[i] = (const short8*)(lds + (ra * 4 + ((quad + (ra >> 1)) & 3)) * 16);
        int rb = wn * 64 + i * 16 + mrow;
        bLds[i] = (const short8*)(lds + 8192 + (rb * 4 + ((quad + (rb >> 1)) & 3)) * 16);
    }

    f32x4 acc[4][4] = {};
    for (int k0 = 0; k0 < K; k0 += BK) {
        #pragma unroll
        for (int it = 0; it < 4; ++it)
            gload_lds16(gptr[it] + 2 * k0, lptr[it]);
        __syncthreads();                         // drains vmcnt -> LDS valid
        short8 af[4], bf[4];
        #pragma unroll
        for (int i = 0; i < 4; ++i) { af[i] = *aLds[i]; bf[i] = *bLds[i]; }
        #pragma unroll
        for (int i = 0; i < 4; ++i)
            #pragma unroll
            for (int j = 0; j < 4; ++j)
                acc[i][j] = __builtin_amdgcn_mfma_f32_16x16x32_bf16(af[i], bf[j], acc[i][j], 0, 0, 0);
        __syncthreads();                         // protect LDS before restage
    }

    // --- epilogue: D row = quad*4 + reg, col = lane&15 (m89-verified layout)
    #pragma unroll
    for (int i = 0; i < 4; ++i) {
        #pragma unroll
        for (int j = 0; j < 4; ++j) {
            int colg = bn * 128 + wn * 64 + j * 16 + mrow;
            #pragma unroll
            for (int r = 0; r < 4; ++r) {
                int rowg = bm * 128 + wm * 64 + i * 16 + quad * 4 + r;
                if (MODE == 0) {
                    ((u16*)Cv)[(size_t)rowg * ldc + colg] = f2bf(acc[i][j][r]);
                } else {
                    ((float*)Cv)[(size_t)rowg * ldc + colg] = acc[i][j][r] + bias[colg];
                }
            }
        }
    }
}

// ---------------------------------------------------------------------------
// Attention: one wave per (b, h, ti). ti==0 copies BOS v; ti>=1 handles grid
// query t=ti-1 (query row p=t+1 in QKV). Slots: BOS(p=0) + in-bounds window
// neighbors nb<=t (p=nb+1). lane=dim(64), online softmax, fp32 math.
// QKV layout: (b*4096+p) x 1536 = [Q | K | V], head h -> cols h*64..h*64+63.
// ---------------------------------------------------------------------------
__global__ __launch_bounds__(256)
void attn_kernel(const u16* __restrict__ QKV, u16* __restrict__ O) {
    const int wid  = blockIdx.x * 4 + (threadIdx.x >> 6);
    const int lane = threadIdx.x & 63;
    const int bh = wid >> 12;            // 16
    const int ti = wid & 4095;           // 4096
    const int b = bh >> 3, h = bh & 7;
    const size_t baseQ = (size_t)b * T_TOK * NQKV;
    const size_t baseO = (size_t)b * T_TOK * DIM;
    const int col = h * 64 + lane;

    if (ti == 0) {                        // output row 0 = bos_v
        O[baseO + col] = QKV[baseQ + 1024 + col];
        return;
    }
    const int t = ti - 1;                 // grid position, 0..4094
    const float qv = b2f(QKV[baseQ + (size_t)(t + 1) * NQKV + col]) * 0.125f;

    float m = -3.0e38f, l = 0.f, acc = 0.f;
    auto process = [&](int p) {
        float kv = b2f(QKV[baseQ + (size_t)p * NQKV + 512 + col]);
        float s = qv * kv;
        #pragma unroll
        for (int off = 32; off >= 1; off >>= 1) s += __shfl_xor(s, off, 64);
        float mn = fmaxf(m, s);
        float alpha = __expf(m - mn);     // exp(-inf)=0 on first slot
        float pe = __expf(s - mn);
        l = l * alpha + pe;
        float vv = b2f(QKV[baseQ + (size_t)p * NQKV + 1024 + col]);
        acc = acc * alpha + pe * vv;
        m = mn;
    };
    process(0);                           // BOS, never masked
    const int f = t >> 10, rem = t & 1023, hh = rem >> 5, ww = rem & 31;
    for (int df = -1; df <= 1; ++df) {
        int nf = f + df; if ((unsigned)nf >= 4u) continue;
        for (int dh = -1; dh <= 1; ++dh) {
            int nh = hh + dh; if ((unsigned)nh >= 32u) continue;
            for (int dw = -1; dw <= 1; ++dw) {
                int nw = ww + dw; if ((unsigned)nw >= 32u) continue;
                int nb = (nf << 10) | (nh << 5) | nw;
                if (nb > t) continue;     // causal (OOB slots always masked)
                process(nb + 1);
            }
        }
    }
    O[baseO + (size_t)ti * DIM + col] = f2bf(acc / l);
}

// ---------------------------------------------------------------------------
// launch: cast -> gemm1 (QKV) -> attn -> gemm2 (out proj + bias)
// ws layout (bytes): xb 8M @0 | Wt 1.5M @8388608 | Wot 0.5M @9961472 |
//                    QKV 24M @10485760 | O aliases xb @0   (total ~34MB)
// ---------------------------------------------------------------------------
extern "C" void kernel_launch(void* const* d_in, const int* in_sizes, int n_in,
                              void* d_out, int out_size, void* d_ws, size_t ws_size,
                              hipStream_t stream) {
    const float* x   = (const float*)d_in[0];
    const float* Wq  = (const float*)d_in[1];
    const float* Wkv = (const float*)d_in[2];
    const float* Wo  = (const float*)d_in[3];
    const float* bo  = (const float*)d_in[4];
    float* out = (float*)d_out;
    char* ws = (char*)d_ws;

    u16* xb  = (u16*)(ws + 0);
    u16* Wt  = (u16*)(ws + 8388608);
    u16* Wot = (u16*)(ws + 9961472);
    u16* QKV = (u16*)(ws + 10485760);
    u16* O   = (u16*)(ws + 0);          // aliases xb (dead after gemm1)

    cast_x_kernel<<<dim3(4096), dim3(256), 0, stream>>>((const float4*)x, xb);
    cast_w_kernel<<<dim3(4096), dim3(256), 0, stream>>>(Wq, Wkv, Wo, Wt, Wot);
    gemm_nt<0><<<dim3(12, 64), dim3(256), 0, stream>>>(xb, Wt, (void*)QKV, nullptr, 512, 512, 1536);
    attn_kernel<<<dim3(16384), dim3(256), 0, stream>>>(QKV, O);
    gemm_nt<1><<<dim3(4, 64), dim3(256), 0, stream>>>(O, Wot, (void*)out, bo, 512, 512, 512);
}

// Round 2
// 142.212 us; speedup vs baseline: 1.3097x; 1.3097x over previous
//
#include <hip/hip_runtime.h>

// ---------------------------------------------------------------------------
// Sparse3DNA: x->QKV proj (bf16 MFMA GEMM), 3x3x3 causal window attention
// (+BOS), output proj. Shapes: b=2, T=4096 (4x32x32), DIM=512, 8 heads x 64.
// ---------------------------------------------------------------------------

#define T_TOK   4096
#define BATCH   2
#define MROWS   (BATCH * T_TOK)     // 8192
#define DIM     512
#define NQKV    1536

typedef unsigned short u16;
typedef unsigned int   u32;
typedef unsigned long long u64;
typedef __attribute__((ext_vector_type(8))) short short8;   // 8 bf16 (4 VGPR)
typedef __attribute__((ext_vector_type(4))) float f32x4;

__device__ __forceinline__ u16 f2bf(float f) {           // RNE float->bf16
    u32 u = __float_as_uint(f);
    return (u16)((u + 0x7fffu + ((u >> 16) & 1u)) >> 16);
}
__device__ __forceinline__ float b2f(u16 u) {
    return __uint_as_float(((u32)u) << 16);
}

__device__ __forceinline__ void gload_lds16(const void* g, void* l) {
    // async global->LDS, 16B/lane; LDS dest = wave-uniform base + lane*16
    __builtin_amdgcn_global_load_lds(
        (const __attribute__((address_space(1))) void*)g,
        (__attribute__((address_space(3))) void*)l, 16, 0, 0);
}

// ---------------------------------------------------------------------------
// merged cast kernel: blocks [0,4096) cast x -> bf16; [4096,8192) transpose+
// cast weights.  Wt[n][k] = [Wq|Wk|Wv](k,n) (1536x512), Wot[n][k] = Wo[k][n].
// ---------------------------------------------------------------------------
__global__ void cast_all_kernel(const float4* __restrict__ x,
                                const float* __restrict__ Wq, const float* __restrict__ Wkv,
                                const float* __restrict__ Wo,
                                u16* __restrict__ xb, u16* __restrict__ Wt,
                                u16* __restrict__ Wot) {
    int blk = blockIdx.x;
    if (blk < 4096) {
        int i = blk * 256 + threadIdx.x;          // 1,048,576 float4s
        float4 v = x[i];
        u64 pack = (u64)f2bf(v.x) | ((u64)f2bf(v.y) << 16) |
                   ((u64)f2bf(v.z) << 32) | ((u64)f2bf(v.w) << 48);
        ((u64*)xb)[i] = pack;
    } else {
        int idx = (blk - 4096) * 256 + threadIdx.x;   // 1,048,576 total
        if (idx < 786432) {
            int k = idx / 1536, n = idx % 1536;       // coalesced reads
            float v = (n < 512) ? Wq[k * 512 + n] : Wkv[k * 1024 + (n - 512)];
            Wt[n * 512 + k] = f2bf(v);
        } else {
            int i2 = idx - 786432;
            int k = i2 >> 9, n = i2 & 511;
            Wot[n * 512 + k] = f2bf(Wo[k * 512 + n]);
        }
    }
}

// ---------------------------------------------------------------------------
// NT GEMM: C(MxN) = A(MxK) * B(NxK)^T, K=512, bf16 in, fp32 acc.
// 128x128 tile / block, 4 waves (2x2), each wave 64x64 via 4x4 mfma 16x16x32.
// BK=32. LDS: A-tile 128x32 + B-tile 128x32 bf16, XOR-swizzled 16B chunks:
//   chunk(row r, kchunk c) -> slot r*4 + ((c + (r>>1)) & 3)
// MODE 0: bf16 store. MODE 1: fp32 store + bias.
// ---------------------------------------------------------------------------
template <int MODE>
__global__ __launch_bounds__(256)
void gemm_nt(const u16* __restrict__ A, const u16* __restrict__ B,
             void* __restrict__ Cv, const float* __restrict__ bias,
             int lda, int ldb, int ldc) {
    constexpr int K = 512, BK = 32;
    __shared__ __align__(16) char lds[16384];    // 8KB A + 8KB B
    const int tid  = threadIdx.x;
    const int lane = tid & 63, wave = tid >> 6;
    const int quad = lane >> 4, mrow = lane & 15;
    const int wm = wave >> 1, wn = wave & 1;
    const int bm = blockIdx.y, bn = blockIdx.x;

    const char* gptr[4];
    char*       lptr[4];
    #pragma unroll
    for (int it = 0; it < 4; ++it) {
        int c   = it * 256 + tid;                // chunk id, lane-consecutive
        int inB = (c >= 512);
        int a   = inB ? c - 512 : c;
        int r   = a >> 2;                        // tile row (0..127)
        int kc  = ((a & 3) - (r >> 1)) & 3;      // inverse swizzle
        int row = (inB ? bn : bm) * 128 + r;
        const u16* base = inB ? B : A;
        int ld = inB ? ldb : lda;
        gptr[it] = (const char*)(base + (size_t)row * ld + kc * 8);
        lptr[it] = (char*)lds + it * 4096 + wave * 1024;   // wave-uniform
    }
    const short8* aLds[4];
    const short8* bLds[4];
    #pragma unroll
    for (int i = 0; i < 4; ++i) {
        int ra = wm * 64 + i * 16 + mrow;
        aLds[i] = (const short8*)(lds + (ra * 4 + ((quad + (ra >> 1)) & 3)) * 16);
        int rb = wn * 64 + i * 16 + mrow;
        bLds[i] = (const short8*)(lds + 8192 + (rb * 4 + ((quad + (rb >> 1)) & 3)) * 16);
    }

    f32x4 acc[4][4] = {};
    for (int k0 = 0; k0 < K; k0 += BK) {
        #pragma unroll
        for (int it = 0; it < 4; ++it)
            gload_lds16(gptr[it] + 2 * k0, lptr[it]);
        __syncthreads();
        short8 af[4], bf[4];
        #pragma unroll
        for (int i = 0; i < 4; ++i) { af[i] = *aLds[i]; bf[i] = *bLds[i]; }
        #pragma unroll
        for (int i = 0; i < 4; ++i)
            #pragma unroll
            for (int j = 0; j < 4; ++j)
                acc[i][j] = __builtin_amdgcn_mfma_f32_16x16x32_bf16(af[i], bf[j], acc[i][j], 0, 0, 0);
        __syncthreads();
    }

    #pragma unroll
    for (int i = 0; i < 4; ++i) {
        #pragma unroll
        for (int j = 0; j < 4; ++j) {
            int colg = bn * 128 + wn * 64 + j * 16 + mrow;
            #pragma unroll
            for (int r = 0; r < 4; ++r) {
                int rowg = bm * 128 + wm * 64 + i * 16 + quad * 4 + r;
                if (MODE == 0) {
                    ((u16*)Cv)[(size_t)rowg * ldc + colg] = f2bf(acc[i][j][r]);
                } else {
                    ((float*)Cv)[(size_t)rowg * ldc + colg] = acc[i][j][r] + bias[colg];
                }
            }
        }
    }
}

// ---------------------------------------------------------------------------
// Attention v2: one wave per (b, h, ti).  Two-phase, branch-free slot set.
//
// Valid neighbor offsets (causal nb<=t <=> (df,dh,dw) lex<= 0): 9x df=-1,
// 3x (0,-1,dw), (0,0,-1), (0,0,0)  => 14 window slots + BOS = 15 (+1 pad).
//
// Phase 1 (score): lane = j*4+g, slot j in [0,16), dim-group g in [0,4).
//   Each lane: 16-dim partial dot (2x short8 loads), reduce over g (2 shfl).
//   Batched softmax across j: 4-shfl max, ONE exp, 4-shfl sum.
// Phase 2 (PV): lane = dim. 15 readlane-broadcast (p_j, pe_j) pairs, scalar
//   coalesced v loads, fma. out = acc/l.
// QKV row p: [Q | K | V], head h -> cols h*64..h*64+63. p = nb+1; p=0 is BOS.
// ---------------------------------------------------------------------------
__global__ __launch_bounds__(256)
void attn_kernel(const u16* __restrict__ QKV, u16* __restrict__ O) {
    const int wid  = blockIdx.x * 4 + (threadIdx.x >> 6);
    const int lane = threadIdx.x & 63;
    const int bh = wid >> 12;            // 16
    const int ti = wid & 4095;           // 4096
    const int b = bh >> 3, h = bh & 7;
    const size_t baseQ = (size_t)b * T_TOK * NQKV;
    const size_t baseO = (size_t)b * T_TOK * DIM;

    if (ti == 0) {                        // output row 0 = bos_v
        O[baseO + h * 64 + lane] = QKV[baseQ + 1024 + h * 64 + lane];
        return;
    }
    const int t = ti - 1;                 // grid position, 0..4094
    const int f = t >> 10, hh = (t >> 5) & 31, ww = t & 31;

    // ---- per-lane slot decode (wave-uniform t; j varies per lane)
    const int j = lane >> 2, g = lane & 3;
    int jm1 = j - 1;
    int dh9 = ((jm1 * 11) >> 5) - 1;      // j in 1..9: (j-1)/3 - 1
    int dw9 = jm1 - (dh9 + 1) * 3 - 1;    // j in 1..9: (j-1)%3 - 1
    int df = (j >= 1 && j <= 9) ? -1 : 0;
    int dh = (j >= 1 && j <= 9) ? dh9 : ((j >= 10 && j <= 12) ? -1 : 0);
    int dw = (j >= 1 && j <= 9) ? dw9 :
             ((j >= 10 && j <= 12) ? (j - 11) : ((j == 13) ? -1 : 0));
    int nf = f + df, nh = hh + dh, nw = ww + dw;
    int valid = (nf >= 0) && ((unsigned)nh < 32u) && ((unsigned)nw < 32u)
                && (j >= 1) && (j <= 14);
    int p = valid ? (t + 1 + df * 1024 + dh * 32 + dw) : 0;   // j==0 -> p=0 (BOS)
    int score_on = valid || (j == 0);

    // ---- phase 1: scores
    const u16* qrow = QKV + baseQ + (size_t)(t + 1) * NQKV + h * 64 + g * 16;
    short8 q0 = *(const short8*)qrow;
    short8 q1 = *(const short8*)(qrow + 8);
    const u16* krow = QKV + baseQ + (size_t)p * NQKV + 512 + h * 64 + g * 16;
    short8 k0 = *(const short8*)krow;
    short8 k1 = *(const short8*)(krow + 8);
    float s = 0.f;
    #pragma unroll
    for (int i = 0; i < 8; ++i) {
        s += b2f((u16)q0[i]) * b2f((u16)k0[i]);
        s += b2f((u16)q1[i]) * b2f((u16)k1[i]);
    }
    s += __shfl_xor(s, 1);
    s += __shfl_xor(s, 2);                // all 4 g-lanes of slot j hold dot_j
    s *= 0.125f;                          // SCALE
    s = score_on ? s : -3.0e38f;

    float m = s;
    #pragma unroll
    for (int off = 4; off <= 32; off <<= 1) m = fmaxf(m, __shfl_xor(m, off));
    float pe = __expf(s - m);             // masked lanes -> 0
    float l = pe;
    #pragma unroll
    for (int off = 4; off <= 32; off <<= 1) l += __shfl_xor(l, off);
    // l = sum_j pe_j (xor over bits 2..5 keeps g fixed), wave-uniform

    // ---- phase 2: PV, lane = dim
    float acc = 0.f;
    const u16* vbase = QKV + baseQ + 1024 + h * 64 + lane;
    #pragma unroll
    for (int jj = 0; jj < 15; ++jj) {
        int   ps = __builtin_amdgcn_readlane(p, jj * 4);
        float pj = __uint_as_float(
                     (u32)__builtin_amdgcn_readlane((int)__float_as_uint(pe), jj * 4));
        float vv = b2f(vbase[(size_t)ps * NQKV]);
        acc += pj * vv;
    }
    O[baseO + (size_t)ti * DIM + h * 64 + lane] = f2bf(acc * __frcp_rn(l));
}

// ---------------------------------------------------------------------------
// launch: cast -> gemm1 (QKV) -> attn -> gemm2 (out proj + bias)
// ws layout (bytes): xb 8M @0 | Wt 1.5M @8388608 | Wot 0.5M @9961472 |
//                    QKV 24M @10485760 | O aliases xb @0   (total ~34MB)
// ---------------------------------------------------------------------------
extern "C" void kernel_launch(void* const* d_in, const int* in_sizes, int n_in,
                              void* d_out, int out_size, void* d_ws, size_t ws_size,
                              hipStream_t stream) {
    const float* x   = (const float*)d_in[0];
    const float* Wq  = (const float*)d_in[1];
    const float* Wkv = (const float*)d_in[2];
    const float* Wo  = (const float*)d_in[3];
    const float* bo  = (const float*)d_in[4];
    float* out = (float*)d_out;
    char* ws = (char*)d_ws;

    u16* xb  = (u16*)(ws + 0);
    u16* Wt  = (u16*)(ws + 8388608);
    u16* Wot = (u16*)(ws + 9961472);
    u16* QKV = (u16*)(ws + 10485760);
    u16* O   = (u16*)(ws + 0);          // aliases xb (dead after gemm1)

    cast_all_kernel<<<dim3(8192), dim3(256), 0, stream>>>(
        (const float4*)x, Wq, Wkv, Wo, xb, Wt, Wot);
    gemm_nt<0><<<dim3(12, 64), dim3(256), 0, stream>>>(xb, Wt, (void*)QKV, nullptr, 512, 512, 1536);
    attn_kernel<<<dim3(16384), dim3(256), 0, stream>>>(QKV, O);
    gemm_nt<1><<<dim3(4, 64), dim3(256), 0, stream>>>(O, Wot, (void*)out, bo, 512, 512, 512);
}